// Round 3
// baseline (38496.454 us; speedup 1.0000x reference)
//
#include <hip/hip_runtime.h>
#include <hip/hip_bf16.h>
#include <hip/hip_cooperative_groups.h>

typedef __attribute__((ext_vector_type(8))) short s8v;   // 8 bf16 MFMA frag
typedef __attribute__((ext_vector_type(4))) float f4v;   // MFMA acc / 4xf32
typedef __attribute__((ext_vector_type(4))) unsigned int u4v; // 16B copy

__device__ __forceinline__ float bf2f(unsigned short u) {
    union { float f; unsigned int i; } v; v.i = ((unsigned int)u) << 16; return v.f;
}
__device__ __forceinline__ unsigned short f2bf(float f) {
    union { float f; unsigned int i; } v; v.f = f;
    unsigned int x = v.i;
    return (unsigned short)((x + 0x7fffu + ((x >> 16) & 1u)) >> 16); // RNE
}
// dtype-flagged scalar load (f32 or bf16 storage)
__device__ __forceinline__ float ldf(const void* p, size_t i, int f32) {
    return f32 ? ((const float*)p)[i] : bf2f(((const unsigned short*)p)[i]);
}

// ---------------- dtype detector ----------------
// flags[0]: 1 if float arrays are f32 storage, 0 if bf16.
// flags[1]: reset encoding 0=int32 1=int8 2=bf16 3=f32 4=int64
__global__ void detect_k(const unsigned short* __restrict__ xu,
                         const unsigned int* __restrict__ rw,
                         int* __restrict__ flags) {
    __shared__ int cnt;
    int tid = threadIdx.x;
    if (tid == 0) cnt = 0;
    __syncthreads();
    int bad = 0;
    for (int i = tid; i < 4096; i += 256) {
        unsigned short v = xu[i];
        int e = (v >> 7) & 0xFF;
        if (e == 0xFF || (e <= 90 && (v & 0x7FFFu) != 0)) bad++;
    }
    atomicAdd(&cnt, bad);
    __syncthreads();
    if (tid == 0) {
        flags[0] = (cnt > 16) ? 1 : 0;
        bool w01 = true, oddz = true, ones = false, b01 = true, h16 = true, fv = true;
        for (int i = 0; i < 32; ++i) {
            unsigned int w = rw[i];
            if (w > 1u) w01 = false;
            if ((i & 1) && w != 0u) oddz = false;
            if (w != 0u) ones = true;
            if ((w & 0xFFu) > 1u || ((w >> 8) & 0xFFu) > 1u ||
                ((w >> 16) & 0xFFu) > 1u || (w >> 24) > 1u) b01 = false;
            unsigned int lo = w & 0xFFFFu, hi = w >> 16;
            if (!((lo == 0u || lo == 0x3F80u) && (hi == 0u || hi == 0x3F80u))) h16 = false;
            if (!(w == 0u || w == 0x3F800000u)) fv = false;
        }
        int mode;
        if (w01 && oddz && ones) mode = 4;      // int64
        else if (w01) mode = 0;                 // int32
        else if (fv) mode = 3;                  // f32 0.0/1.0
        else if (h16) mode = 2;                 // bf16 0.0/1.0
        else if (b01) mode = 1;                 // int8
        else mode = 0;
        flags[1] = mode;
    }
}

__device__ __forceinline__ int get_reset(const void* p, int mode, int idx) {
    switch (mode) {
        case 0: return ((const int*)p)[idx] != 0;
        case 1: return ((const signed char*)p)[idx] != 0;
        case 2: return ((const unsigned short*)p)[idx] != 0;
        case 3: return ((const float*)p)[idx] != 0.f;
        default: return ((const int*)p)[idx * 2] != 0;
    }
}

// stage 24 weight columns {j0..j0+7, 1024+.., 2048+..} of a [1024][3072]
// matrix into lws rows 0..23 (row stride 1048), converting f32->bf16 if needed
__device__ __forceinline__ void stage_w(const void* w, int wf32, int j0, int tid,
                                        unsigned short* lws) {
    for (int k = tid; k < 1024; k += 256) {
        #pragma unroll
        for (int g = 0; g < 3; ++g) {
            unsigned short tmp[8];
            size_t base = (size_t)k * 3072 + g * 1024 + j0;
            if (wf32) {
                const float* wf = (const float*)w;
                f4v v0 = *(const f4v*)&wf[base];
                f4v v1 = *(const f4v*)&wf[base + 4];
                #pragma unroll
                for (int r = 0; r < 4; ++r) { tmp[r] = f2bf(v0[r]); tmp[4 + r] = f2bf(v1[r]); }
            } else {
                union { u4v v; unsigned short u[8]; } cv;
                cv.v = *(const u4v*)&((const unsigned short*)w)[base];
                #pragma unroll
                for (int r = 0; r < 8; ++r) tmp[r] = cv.u[r];
            }
            #pragma unroll
            for (int r = 0; r < 8; ++r) lws[(g * 8 + r) * 1048 + k] = tmp[r];
        }
    }
}

// ---------------- persistent cooperative scan (whole GRU) ----------------
// 128 blocks x 256 threads; block b owns h-dims j0=8b..8b+7. Per phase one
// 16x16 MFMA tile (M=batch=16), K=1024 split over 4 waves, LDS reduce.
// Weights live in per-lane registers (LDS bounce at init).
__global__ __launch_bounds__(256) void scan_k(
    const void* __restrict__ xv, const void* __restrict__ resetv,
    const void* __restrict__ carryv, const void* __restrict__ inithv,
    const void* __restrict__ wiv, const void* __restrict__ whv,
    const void* __restrict__ biasv, void* __restrict__ outv,
    unsigned short* __restrict__ heff, unsigned short* __restrict__ rh,
    const int* __restrict__ flags) {
    __shared__ __align__(16) unsigned short lws[24 * 1048];
    __shared__ __align__(16) float lpart[4 * 256];
    __shared__ float lhe[128];

    cooperative_groups::grid_group grid = cooperative_groups::this_grid();

    const int xf32 = flags[0];
    const int rmode = flags[1];

    const int tid = threadIdx.x;
    const int wave = tid >> 6, lane = tid & 63;
    const int c = lane & 15, q = lane >> 4;   // MFMA lane roles
    const int j0 = blockIdx.x * 8;
    const int an = tid & 15, ac = tid >> 4;   // elementwise roles
    const int jloc = ac & 7, jg = j0 + jloc;
    const bool owner = (ac < 8);
    const int colA = owner ? jg : (1024 + jg);
    const int colB = 2048 + jg;
    const float biasA = ldf(biasv, colA, xf32);
    const float biasB = ldf(biasv, colB, xf32);
    const float initj = ldf(inithv, jg, xf32);
    const unsigned short initj_b = f2bf(initj);
    const int kbase = wave * 256;

    // ---- weights -> registers via LDS bounce ----
    s8v whA[8], whB[8], wiA[8], wiB[8];
    stage_w(whv, xf32, j0, tid, lws);
    __syncthreads();
    #pragma unroll
    for (int kc = 0; kc < 8; ++kc) {
        int kk = kbase + kc * 32 + q * 8;
        whA[kc] = *(const s8v*)&lws[c * 1048 + kk];
        whB[kc] = *(const s8v*)&lws[(16 + (c & 7)) * 1048 + kk];
    }
    __syncthreads();
    stage_w(wiv, xf32, j0, tid, lws);
    __syncthreads();
    #pragma unroll
    for (int kc = 0; kc < 8; ++kc) {
        int kk = kbase + kc * 32 + q * 8;
        wiA[kc] = *(const s8v*)&lws[c * 1048 + kk];
        wiB[kc] = *(const s8v*)&lws[(16 + (c & 7)) * 1048 + kk];
    }

    // ---- h0 = reset[:,0] ? initial_h : carry[:,0,:]; third output ----
    float hreg = 0.f, zreg = 0.f, he_own = 0.f;
    if (owner) {
        int rs0 = get_reset(resetv, rmode, an * 1024);
        float h0 = rs0 ? initj : ldf(carryv, (size_t)an * 1048576 + jg, xf32);
        unsigned short hb0 = f2bf(h0);
        heff[an * 1024 + jg] = hb0;
        hreg = bf2f(hb0);
        if (an == 0) {
            if (xf32) ((float*)outv)[(size_t)33554432 + jg] = initj;
            else ((unsigned short*)outv)[(size_t)33554432 + jg] = initj_b;
        }
    }
    __syncthreads();
    grid.sync();

    for (int t = 0; t < 1024; ++t) {
        int rs = owner ? get_reset(resetv, rmode, an * 1024 + t) : 0;
        if (owner) { he_own = rs ? initj : hreg; lhe[an * 8 + jloc] = he_own; }

        // x A-fragments (shared by both phases): A[m=batch=c][k]
        s8v xa[8];
        if (xf32) {
            const float* xf = (const float*)xv;
            #pragma unroll
            for (int kc = 0; kc < 8; ++kc) {
                size_t b = (size_t)c * 1048576 + (size_t)t * 1024 + kbase + kc * 32 + q * 8;
                f4v v0 = *(const f4v*)&xf[b];
                f4v v1 = *(const f4v*)&xf[b + 4];
                union { s8v v; unsigned short u[8]; } cv;
                #pragma unroll
                for (int r = 0; r < 4; ++r) { cv.u[r] = f2bf(v0[r]); cv.u[4 + r] = f2bf(v1[r]); }
                xa[kc] = cv.v;
            }
        } else {
            const unsigned short* xu = (const unsigned short*)xv;
            #pragma unroll
            for (int kc = 0; kc < 8; ++kc) {
                size_t b = (size_t)c * 1048576 + (size_t)t * 1024 + kbase + kc * 32 + q * 8;
                xa[kc] = *(const s8v*)&xu[b];
            }
        }

        // ===== Phase A: zr = sigmoid(x@Wi_zr + h@Wh_zr + b) =====
        f4v acc = (f4v){0.f, 0.f, 0.f, 0.f};
        #pragma unroll
        for (int kc = 0; kc < 8; ++kc) {
            int kk = kbase + kc * 32 + q * 8;
            s8v ha = *(const s8v*)&heff[c * 1024 + kk];
            acc = __builtin_amdgcn_mfma_f32_16x16x32_bf16(ha, whA[kc], acc, 0, 0, 0);
        }
        #pragma unroll
        for (int kc = 0; kc < 8; ++kc)
            acc = __builtin_amdgcn_mfma_f32_16x16x32_bf16(xa[kc], wiA[kc], acc, 0, 0, 0);
        *(f4v*)&lpart[wave * 256 + c * 16 + q * 4] = acc;
        __syncthreads();
        {
            float pre = lpart[ac * 16 + an] + lpart[256 + ac * 16 + an] +
                        lpart[512 + ac * 16 + an] + lpart[768 + ac * 16 + an] + biasA;
            float sg = 1.f / (1.f + expf(-pre));
            if (owner) zreg = sg;
            else rh[an * 1024 + jg] = f2bf(sg * lhe[an * 8 + jloc]);
        }
        grid.sync();

        // ===== Phase B: a = tanh(x@Wi_a + (r*h)@Wh_a + b); combine =====
        f4v acc2 = (f4v){0.f, 0.f, 0.f, 0.f};
        #pragma unroll
        for (int kc = 0; kc < 8; ++kc) {
            int kk = kbase + kc * 32 + q * 8;
            s8v ra = *(const s8v*)&rh[c * 1024 + kk];
            acc2 = __builtin_amdgcn_mfma_f32_16x16x32_bf16(ra, whB[kc], acc2, 0, 0, 0);
        }
        #pragma unroll
        for (int kc = 0; kc < 8; ++kc)
            acc2 = __builtin_amdgcn_mfma_f32_16x16x32_bf16(xa[kc], wiB[kc], acc2, 0, 0, 0);
        *(f4v*)&lpart[wave * 256 + c * 16 + q * 4] = acc2;
        __syncthreads();
        if (owner) {
            float preB = lpart[ac * 16 + an] + lpart[256 + ac * 16 + an] +
                         lpart[512 + ac * 16 + an] + lpart[768 + ac * 16 + an] + biasB;
            float aa = tanhf(preB);
            float hn = (1.f - zreg) * he_own + zreg * aa;
            size_t oidx = ((size_t)an * 1024 + t) * 1024 + jg;
            if (xf32) {
                float* o = (float*)outv;
                o[oidx] = hn;
                o[16777216 + oidx] = hn;
            } else {
                unsigned short* o = (unsigned short*)outv;
                unsigned short hb = f2bf(hn);
                o[oidx] = hb;
                o[16777216 + oidx] = hb;
            }
            hreg = hn;
            int rs2 = (t < 1023) ? get_reset(resetv, rmode, an * 1024 + t + 1) : 0;
            heff[an * 1024 + jg] = rs2 ? initj_b : f2bf(hn);
        }
        grid.sync();
    }
}

extern "C" void kernel_launch(void* const* d_in, const int* in_sizes, int n_in,
                              void* d_out, int out_size, void* d_ws, size_t ws_size,
                              hipStream_t stream) {
    const void* x     = d_in[0];
    const void* reset = d_in[1];
    const void* carry = d_in[2];
    const void* inith = d_in[3];
    const void* w_i   = d_in[4];
    const void* w_h   = d_in[5];
    const void* bias  = d_in[6];

    char* ws = (char*)d_ws;
    unsigned short* heff = (unsigned short*)ws;             // 32 KB
    unsigned short* rh   = (unsigned short*)(ws + 32768);   // 32 KB
    int*            flags = (int*)(ws + 65536);             // 16 B

    detect_k<<<dim3(1), dim3(256), 0, stream>>>(
        (const unsigned short*)x, (const unsigned int*)reset, flags);

    void* kargs[] = { (void*)&x, (void*)&reset, (void*)&carry, (void*)&inith,
                      (void*)&w_i, (void*)&w_h, (void*)&bias, (void*)&d_out,
                      (void*)&heff, (void*)&rh, (void*)&flags };
    hipLaunchCooperativeKernel(reinterpret_cast<const void*>(&scan_k),
                               dim3(128), dim3(256), kargs, 0, stream);
    (void)in_sizes; (void)n_in; (void)out_size; (void)ws_size;
}